// Round 6
// baseline (1703.910 us; speedup 1.0000x reference)
//
#include <hip/hip_runtime.h>
#include <hip/hip_cooperative_groups.h>

namespace cg = cooperative_groups;

#define BN_EPS 1e-3f
#define NREP 16  // BN stat replicas

typedef __attribute__((ext_vector_type(8))) short short8;
typedef __attribute__((ext_vector_type(4))) float float4v;

__device__ __forceinline__ short f2bf(float f) {
    unsigned u = __float_as_uint(f);
    unsigned r = (u + 0x7FFFu + ((u >> 16) & 1u)) >> 16;
    return (short)r;
}

// s_waitcnt vmcnt(N) only
template <int N>
__device__ __forceinline__ void waitcnt_vm() {
    __builtin_amdgcn_s_waitcnt(0xF70 | (N & 15) | ((N >> 4) << 14));
}

// raw s_barrier (no compiler vmcnt(0) drain; we wait explicitly)
__device__ __forceinline__ void wave_barrier() { asm volatile("s_barrier" ::: "memory"); }

// async global -> LDS, 16B/lane; lds dst wave-uniform base + lane*16
__device__ __forceinline__ void dma16(const short* g, short* l) {
    __builtin_amdgcn_global_load_lds((const __attribute__((address_space(1))) void*)g,
                                     (__attribute__((address_space(3))) void*)l, 16, 0, 0);
}

// ---------------- small utility kernels ----------------

__global__ __launch_bounds__(256) void zero_kernel(float* p, int n) {
    int i = blockIdx.x * 256 + threadIdx.x;
    if (i < n) p[i] = 0.f;
}

__global__ __launch_bounds__(256) void copy_kernel(const float* __restrict__ in,
                                                   float* __restrict__ out, int n) {
    int i = blockIdx.x * 256 + threadIdx.x;
    if (i < n) out[i] = in[i];
}

__global__ __launch_bounds__(256) void zero_rows_kernel(short* a, short* b, long maxN) {
    int t = threadIdx.x;
    if (t < 32) a[maxN * 32 + t] = 0;
    else if (t < 96) a[maxN * 64 + (t - 32)] = 0;
    else if (t < 128) b[maxN * 32 + (t - 96)] = 0;
    else if (t < 192) b[maxN * 64 + (t - 128)] = 0;
}

__global__ __launch_bounds__(256) void xyz_kernel(const int* __restrict__ coords,
                                                  float* __restrict__ out, int N,
                                                  float sx, float sy, float sz) {
    int n = blockIdx.x * 256 + threadIdx.x;
    if (n >= N) return;
    int4 c = ((const int4*)coords)[n];
    out[n * 3 + 0] = c.w * sx;
    out[n * 3 + 1] = c.z * sy - 40.0f;
    out[n * 3 + 2] = c.y * sz - 3.0f;
}

__global__ __launch_bounds__(256) void convert_f0(const float* __restrict__ f,
                                                  short* __restrict__ dst, int N) {
    int i = blockIdx.x * 256 + threadIdx.x;
    if (i >= N * 32) return;
    int c = i & 31, n = i >> 5;
    dst[i] = (c < 4) ? f2bf(f[n * 4 + c]) : (short)0;
}

// ---- weight prep: W [K][CI][CO] fp32 -> Wt [K][c*CT+t][quad][l16][8] bf16 ----
struct PrepAll {
    const float* src[14];
    short* dst[14];
    int CI[14];
    int CO[14];
    int CHP[14];
    int cum[15];
};

__global__ __launch_bounds__(256) void prep_all_kernel(PrepAll d) {
    int i = blockIdx.x * 256 + threadIdx.x;
    if (i >= d.cum[14]) return;
    int l = 0;
    while (l < 13 && i >= d.cum[l + 1]) ++l;
    int f = i - d.cum[l];
    int CO = d.CO[l], CI = d.CI[l];
    int NCH = d.CHP[l] / 32, CT = CO / 16;
    int e = f & 7;
    int u = f >> 3;
    int l16 = u & 15;
    int q = (u >> 4) & 3;
    int u2 = u >> 6;
    int t = u2 % CT;
    int c = (u2 / CT) % NCH;
    int k = u2 / (CT * NCH);
    int ci = c * 32 + q * 8 + e;
    int co = t * 16 + l16;
    float v = (ci < CI) ? d.src[l][((size_t)k * CI + ci) * CO + co] : 0.f;
    d.dst[l][f] = f2bf(v);
}

// per-k A fragments for one wave (32 rows x CHP), held in VGPRs
struct ASet {
    short8 v0, v1, v2, v3;  // (mt0,c0) (mt0,c1) (mt1,c0) (mt1,c1)
};

// ---------------- PERSISTENT fused cooperative sparse conv + BN + ReLU ----------------
// Grid is clamped by the host to the co-residency capacity (occupancy query).
// Each block grid-strides over row tiles. If tiles == gridDim.x (common), acc
// stays in VGPRs across grid.sync and BN is applied from registers. Otherwise
// each block spills its tiles' acc to preact (own rows only) and re-reads
// after the sync (L2-mostly). Per-tile: hybrid MFMA conv (A: global->VGPR
// gathers, depth-2 pipeline; B: 3-slot LDS ring; active-k compaction), then
// block BN stats -> replica atomics.
template <int CHP, int CO, int K, bool F32OUT, bool BFOUT, int CHPO>
__global__ __launch_bounds__(256, 4) void sconv_pers(
    const short* __restrict__ feat, const int* __restrict__ rb, const short* __restrict__ Wt,
    const float* __restrict__ g, const float* __restrict__ b, float* __restrict__ stats,
    float* __restrict__ preact, float* __restrict__ fout, short* __restrict__ bfout, int N,
    int zrow, int tiles) {
    constexpr int NCH = CHP / 32;
    constexpr int CT = CO / 16;
    constexpr int BTILE = CO * CHP;    // shorts
    constexpr int NB = BTILE / 512;    // B DMA insts per tile (1KB each)
    constexpr int A = 2 * NCH;         // A loads per wave per tile
    constexpr int ROWS = 128;

    __shared__ __align__(16) short ldsB[3 * BTILE];
    __shared__ int sIdx[K * ROWS];
    __shared__ int sFlag[K];
    __shared__ int sKl[K];
    __shared__ int sKn;

    const int tid = threadIdx.x;
    const int w = tid >> 6;
    const int lane = tid & 63;
    const int quad = lane >> 4;
    const int l16 = lane & 15;
    const bool multi = tiles > (int)gridDim.x;
    const short* fquad = feat + quad * 8;

    auto issueB = [&](int kp, int slot) {
        const short* wk = Wt + (size_t)kp * BTILE + lane * 8;
        short* bb = ldsB + slot * BTILE;
#pragma unroll
        for (int jj = 0; jj < (NB + 3) / 4; ++jj) {
            int j = jj * 4 + w;
            if (j < NB) dma16(wk + j * 512, bb + j * 512);
        }
    };
    auto issueA = [&](int kp) {
        ASet s;
        int i0 = sIdx[kp * ROWS + w * 32 + l16];
        int i1 = sIdx[kp * ROWS + w * 32 + 16 + l16];
        const short* p0 = fquad + (size_t)(i0 < 0 ? zrow : i0) * CHP;
        const short* p1 = fquad + (size_t)(i1 < 0 ? zrow : i1) * CHP;
        s.v0 = *(const short8*)p0;
        s.v2 = *(const short8*)p1;
        if constexpr (NCH == 2) {
            s.v1 = *(const short8*)(p0 + 32);
            s.v3 = *(const short8*)(p1 + 32);
        } else {
            s.v1 = (short8)0;
            s.v3 = (short8)0;
        }
        return s;
    };

    // per-wave wait constant: own B share + own A loads (one tile's worth)
    constexpr int BW0 = NB / 4 + ((NB % 4) > 0 ? 1 : 0);
    constexpr int BW1 = NB / 4 + ((NB % 4) > 1 ? 1 : 0);
    constexpr int BW2 = NB / 4 + ((NB % 4) > 2 ? 1 : 0);
    constexpr int BW3 = NB / 4;

    float4v acc[2][CT];

    for (int tile = blockIdx.x; tile < tiles; tile += gridDim.x) {
        const int m0 = tile * ROWS;

        if (tid < K) sFlag[tid] = 0;
        __syncthreads();
        for (int e = tid; e < K * ROWS; e += 256) {
            int r = m0 + (e & (ROWS - 1));
            int v = (r < N) ? rb[(size_t)(e >> 7) * N + r] : -1;
            sIdx[e] = v;
            if (v >= 0) sFlag[e >> 7] = 1;  // benign race: same value
        }
        __syncthreads();
        if (w == 0) {
            int f = (lane < K) ? sFlag[lane] : 0;
            unsigned long long m = __ballot(f != 0);
            if (f) sKl[__popcll(m & ((1ull << lane) - 1ull))] = lane;
            if (lane == 0) sKn = (int)__popcll(m);
        }
        __syncthreads();
        const int nk = sKn;

#pragma unroll
        for (int mt = 0; mt < 2; ++mt)
#pragma unroll
            for (int t = 0; t < CT; ++t) acc[mt][t] = (float4v)0.f;

        ASet sA{}, sB{}, sC{};
        if (nk > 0) {
            issueB(sKl[0], 0);
            sA = issueA(sKl[0]);
        }
        if (nk > 1) {
            issueB(sKl[1], 1);
            sB = issueA(sKl[1]);
        }

        int slotRd = 0, slotWr = 2;
        for (int i = 0; i < nk; ++i) {
            if (i < nk - 1) {
                if (w == 0) waitcnt_vm<BW0 + A>();
                else if (w == 1) waitcnt_vm<BW1 + A>();
                else if (w == 2) waitcnt_vm<BW2 + A>();
                else waitcnt_vm<BW3 + A>();
            } else {
                waitcnt_vm<0>();
            }
            __builtin_amdgcn_sched_barrier(0);
            wave_barrier();
            if (i + 2 < nk) {
                issueB(sKl[i + 2], slotWr);
                sC = issueA(sKl[i + 2]);
            }
            const short* bb = ldsB + slotRd * BTILE;
#pragma unroll
            for (int c = 0; c < NCH; ++c) {
#pragma unroll
                for (int t = 0; t < CT; ++t) {
                    short8 bf = *(const short8*)(bb + ((c * CT + t) * 64 + quad * 16 + l16) * 8);
#pragma unroll
                    for (int mt = 0; mt < 2; ++mt) {
                        short8 af = (mt == 0) ? ((c == 0) ? sA.v0 : sA.v1)
                                              : ((c == 0) ? sA.v2 : sA.v3);
                        acc[mt][t] =
                            __builtin_amdgcn_mfma_f32_16x16x32_bf16(af, bf, acc[mt][t], 0, 0, 0);
                    }
                }
            }
            sA = sB;
            sB = sC;
            slotRd = (slotRd == 2) ? 0 : slotRd + 1;
            slotWr = (slotWr == 2) ? 0 : slotWr + 1;
        }

        // ---- per-tile block BN stats -> replica atomics ----
        __syncthreads();  // MFMA LDS reads done; ldsB reusable as float scratch
        float* red = (float*)ldsB;
#pragma unroll
        for (int t = 0; t < CT; ++t) {
            float s = 0.f, ss = 0.f;
#pragma unroll
            for (int mt = 0; mt < 2; ++mt)
#pragma unroll
                for (int r = 0; r < 4; ++r) {
                    int orow = m0 + w * 32 + mt * 16 + quad * 4 + r;
                    float v = (orow < N) ? acc[mt][t][r] : 0.f;
                    s += v;
                    ss += v * v;
                }
            s += __shfl_xor(s, 16);
            s += __shfl_xor(s, 32);
            ss += __shfl_xor(ss, 16);
            ss += __shfl_xor(ss, 32);
            if (lane < 16) {
                red[w * 2 * CO + t * 16 + lane] = s;
                red[w * 2 * CO + CO + t * 16 + lane] = ss;
            }
        }
        __syncthreads();
        if (tid < 2 * CO) {
            float v = red[tid] + red[2 * CO + tid] + red[4 * CO + tid] + red[6 * CO + tid];
            float* st = stats + (size_t)(tile & (NREP - 1)) * 128;
            atomicAdd(&st[(tid < CO) ? tid : (64 + tid - CO)], v);
        }
        // red reads complete before next tile's ldsB DMA (two barriers in between)

        if (multi) {  // spill this tile's acc to preact (own rows only)
#pragma unroll
            for (int mt = 0; mt < 2; ++mt)
#pragma unroll
                for (int t = 0; t < CT; ++t) {
                    int col = t * 16 + l16;
#pragma unroll
                    for (int r = 0; r < 4; ++r) {
                        int orow = m0 + w * 32 + mt * 16 + quad * 4 + r;
                        if (orow < N) preact[(size_t)orow * CO + col] = acc[mt][t][r];
                    }
                }
        }
    }

    // ---- grid-wide sync: all blocks' stats atomics complete ----
    cg::this_grid().sync();

    // ---- BN finalize: scale/shift into LDS ----
    float* red = (float*)ldsB;
    __syncthreads();
    if (tid < CO) {
        float s = 0.f, q = 0.f;
#pragma unroll
        for (int r2 = 0; r2 < NREP; ++r2) {
            s += __hip_atomic_load(&stats[r2 * 128 + tid], __ATOMIC_RELAXED,
                                   __HIP_MEMORY_SCOPE_AGENT);
            q += __hip_atomic_load(&stats[r2 * 128 + 64 + tid], __ATOMIC_RELAXED,
                                   __HIP_MEMORY_SCOPE_AGENT);
        }
        float inv = 1.0f / (float)N;
        float m = s * inv;
        float v = q * inv - m * m;
        float sc = g[tid] / sqrtf(v + BN_EPS);
        red[tid] = sc;
        red[CO + tid] = b[tid] - m * sc;
    }
    __syncthreads();

    if (!multi) {
        // exactly one tile per block; acc still live in registers
        const int m0 = blockIdx.x * ROWS;
#pragma unroll
        for (int mt = 0; mt < 2; ++mt)
#pragma unroll
            for (int t = 0; t < CT; ++t) {
                int col = t * 16 + l16;
                float sc = red[col];
                float sh = red[CO + col];
#pragma unroll
                for (int r = 0; r < 4; ++r) {
                    int orow = m0 + w * 32 + mt * 16 + quad * 4 + r;
                    if (orow < N) {
                        float y = fmaxf(acc[mt][t][r] * sc + sh, 0.f);
                        if constexpr (F32OUT) fout[(size_t)orow * CO + col] = y;
                        if constexpr (BFOUT) {
                            bfout[(size_t)orow * CHPO + col] = f2bf(y);
                            if constexpr (CHPO > CO)
                                bfout[(size_t)orow * CHPO + CO + l16] = 0;
                        }
                    }
                }
            }
    } else {
        for (int tile = blockIdx.x; tile < tiles; tile += gridDim.x) {
            const int m0 = tile * ROWS;
#pragma unroll
            for (int mt = 0; mt < 2; ++mt)
#pragma unroll
                for (int t = 0; t < CT; ++t) {
                    int col = t * 16 + l16;
                    float sc = red[col];
                    float sh = red[CO + col];
#pragma unroll
                    for (int r = 0; r < 4; ++r) {
                        int orow = m0 + w * 32 + mt * 16 + quad * 4 + r;
                        if (orow < N) {
                            float y = fmaxf(preact[(size_t)orow * CO + col] * sc + sh, 0.f);
                            if constexpr (F32OUT) fout[(size_t)orow * CO + col] = y;
                            if constexpr (BFOUT) {
                                bfout[(size_t)orow * CHPO + col] = f2bf(y);
                                if constexpr (CHPO > CO)
                                    bfout[(size_t)orow * CHPO + CO + l16] = 0;
                            }
                        }
                    }
                }
        }
    }
}

// ---------------- host helper ----------------

template <int CHP, int CO, int K, bool F32OUT, bool BFOUT, int CHPO>
static void layer(const short* fin, const int* rb, const short* wt, const float* g,
                  const float* b, float* stats, float* preact, float* fout, short* bfout, int N,
                  int zrow, hipStream_t stream) {
    auto kfn = sconv_pers<CHP, CO, K, F32OUT, BFOUT, CHPO>;
    static int maxB = 0;  // per-instantiation cache
    if (maxB == 0) {
        int m = 0;
        if (hipOccupancyMaxActiveBlocksPerMultiprocessor(&m, kfn, 256, 0) != hipSuccess || m < 1)
            m = 1;
        maxB = m;
    }
    int tiles = (N + 127) / 128;
    int cap = maxB * 256;  // 256 CUs on MI355X
    int grid = tiles < cap ? tiles : cap;
    void* args[] = {(void*)&fin,   (void*)&rb,   (void*)&wt,    (void*)&g,   (void*)&b,
                    (void*)&stats, (void*)&preact, (void*)&fout, (void*)&bfout, (void*)&N,
                    (void*)&zrow,  (void*)&tiles};
    while (grid >= 1) {
        hipError_t e = hipLaunchCooperativeKernel(reinterpret_cast<void*>(kfn), dim3(grid),
                                                  dim3(256), args, 0, stream);
        if (e == hipSuccess) break;
        grid >>= 1;  // safety net: shrink until the runtime accepts co-residency
    }
}

extern "C" void kernel_launch(void* const* d_in, const int* in_sizes, int n_in, void* d_out,
                              int out_size, void* d_ws, size_t ws_size, hipStream_t stream) {
    const float* features = (const float*)d_in[0];
    const float* W[14];
    const float* G[14];
    const float* Bb[14];
    for (int i = 0; i < 14; ++i) {
        W[i] = (const float*)d_in[1 + 3 * i];
        G[i] = (const float*)d_in[2 + 3 * i];
        Bb[i] = (const float*)d_in[3 + 3 * i];
    }
    const int* coords0 = (const int*)d_in[43];
    const int* coords1 = (const int*)d_in[44];
    const int* coords2 = (const int*)d_in[45];
    const int* coords3 = (const int*)d_in[46];
    const int* rb0 = (const int*)d_in[47];
    const int* rbc1 = (const int*)d_in[48];
    const int* rb1 = (const int*)d_in[49];
    const int* rbc2 = (const int*)d_in[50];
    const int* rb2 = (const int*)d_in[51];
    const int* rbc3 = (const int*)d_in[52];
    const int* rb3 = (const int*)d_in[53];
    const int* rbc4 = (const int*)d_in[54];

    const int N0 = in_sizes[0] / 4;
    const int N1 = in_sizes[44] / 4;
    const int N2 = in_sizes[45] / 4;
    const int N3 = in_sizes[46] / 4;
    const int N4 = in_sizes[54] / 3;

    float* out = (float*)d_out;
    long off = 0;
    float* xyz0 = out + off; off += (long)N0 * 3;
    float* f0   = out + off; off += (long)N0 * 4;
    float* xyz1 = out + off; off += (long)N1 * 3;
    float* f1   = out + off; off += (long)N1 * 32;
    float* xyz2 = out + off; off += (long)N2 * 3;
    float* f2   = out + off; off += (long)N2 * 64;
    float* xyz3 = out + off; off += (long)N3 * 3;
    float* f3   = out + off; off += (long)N3 * 64;
    float* f4   = out + off;

    long maxN = N0;
    if (N1 > maxN) maxN = N1;
    if (N2 > maxN) maxN = N2;
    if (N3 > maxN) maxN = N3;
    if (N4 > maxN) maxN = N4;
    const int zrow = (int)maxN;

    float* preact = (float*)d_ws;                         // maxN*64 fp32 (spill path)
    float* statsBase = preact + (size_t)maxN * 64;        // 14 * NREP * 128 fp32
    short* bfA = (short*)(statsBase + 14 * NREP * 128);   // (maxN+1)*64 bf16
    short* bfB = bfA + (size_t)(maxN + 1) * 64;           // (maxN+1)*64 bf16
    short* wtBase = bfB + (size_t)(maxN + 1) * 64;        // swizzled bf16 weights

    static const int KK[14] = {27, 27, 27, 27, 27, 27, 27, 27, 27, 27, 27, 27, 27, 3};
    static const int CI[14] = {4, 16, 16, 32, 32, 32, 64, 64, 64, 64, 64, 64, 64, 64};
    static const int CO[14] = {16, 16, 32, 32, 32, 64, 64, 64, 64, 64, 64, 64, 64, 64};
    short* WT[14];
    PrepAll pd;
    {
        size_t o = 0;
        int cum = 0;
        for (int l = 0; l < 14; ++l) {
            WT[l] = wtBase + o;
            int chp = CI[l] <= 32 ? 32 : 64;
            pd.src[l] = W[l];
            pd.dst[l] = WT[l];
            pd.CI[l] = CI[l];
            pd.CO[l] = CO[l];
            pd.CHP[l] = chp;
            pd.cum[l] = cum;
            cum += KK[l] * CO[l] * chp;
            o += (size_t)KK[l] * CO[l] * chp;
        }
        pd.cum[14] = cum;
    }

    int nstats = 14 * NREP * 128;
    hipLaunchKernelGGL(zero_kernel, dim3((nstats + 255) / 256), dim3(256), 0, stream, statsBase,
                       nstats);
    hipLaunchKernelGGL(zero_rows_kernel, dim3(1), dim3(256), 0, stream, bfA, bfB, maxN);
    hipLaunchKernelGGL(prep_all_kernel, dim3((pd.cum[14] + 255) / 256), dim3(256), 0, stream, pd);

    hipLaunchKernelGGL(copy_kernel, dim3((N0 * 4 + 255) / 256), dim3(256), 0, stream, features, f0,
                       N0 * 4);
    hipLaunchKernelGGL(xyz_kernel, dim3((N0 + 255) / 256), dim3(256), 0, stream, coords0, xyz0, N0,
                       0.05f, 0.05f, 0.1f);
    hipLaunchKernelGGL(xyz_kernel, dim3((N1 + 255) / 256), dim3(256), 0, stream, coords1, xyz1, N1,
                       0.1f, 0.1f, 0.2f);
    hipLaunchKernelGGL(xyz_kernel, dim3((N2 + 255) / 256), dim3(256), 0, stream, coords2, xyz2, N2,
                       0.2f, 0.2f, 0.4f);
    hipLaunchKernelGGL(xyz_kernel, dim3((N3 + 255) / 256), dim3(256), 0, stream, coords3, xyz3, N3,
                       0.4f, 0.4f, 0.8f);
    hipLaunchKernelGGL(convert_f0, dim3((N0 * 32 + 255) / 256), dim3(256), 0, stream, features,
                       bfA, N0);

    float* st = statsBase;
#define STAT(l) (st + (size_t)(l)*NREP * 128)

    layer<32, 16, 27, false, true, 32>(bfA, rb0, WT[0], G[0], Bb[0], STAT(0), preact, nullptr, bfB,
                                       N0, zrow, stream);
    layer<32, 16, 27, false, true, 32>(bfB, rb0, WT[1], G[1], Bb[1], STAT(1), preact, nullptr, bfA,
                                       N0, zrow, stream);
    layer<32, 32, 27, true, true, 32>(bfA, rbc1, WT[2], G[2], Bb[2], STAT(2), preact, f1, bfB, N1,
                                      zrow, stream);

    layer<32, 32, 27, false, true, 32>(bfB, rb1, WT[3], G[3], Bb[3], STAT(3), preact, nullptr, bfA,
                                       N1, zrow, stream);
    layer<32, 32, 27, false, true, 32>(bfA, rb1, WT[4], G[4], Bb[4], STAT(4), preact, nullptr, bfB,
                                       N1, zrow, stream);
    layer<32, 64, 27, true, true, 64>(bfB, rbc2, WT[5], G[5], Bb[5], STAT(5), preact, f2, bfA, N2,
                                      zrow, stream);

    layer<64, 64, 27, false, true, 64>(bfA, rb2, WT[6], G[6], Bb[6], STAT(6), preact, nullptr, bfB,
                                       N2, zrow, stream);
    layer<64, 64, 27, false, true, 64>(bfB, rb2, WT[7], G[7], Bb[7], STAT(7), preact, nullptr, bfA,
                                       N2, zrow, stream);
    layer<64, 64, 27, false, true, 64>(bfA, rb2, WT[8], G[8], Bb[8], STAT(8), preact, nullptr, bfB,
                                       N2, zrow, stream);
    layer<64, 64, 27, true, true, 64>(bfB, rbc3, WT[9], G[9], Bb[9], STAT(9), preact, f3, bfA, N3,
                                      zrow, stream);

    layer<64, 64, 27, false, true, 64>(bfA, rb3, WT[10], G[10], Bb[10], STAT(10), preact, nullptr,
                                       bfB, N3, zrow, stream);
    layer<64, 64, 27, false, true, 64>(bfB, rb3, WT[11], G[11], Bb[11], STAT(11), preact, nullptr,
                                       bfA, N3, zrow, stream);
    layer<64, 64, 27, false, true, 64>(bfA, rb3, WT[12], G[12], Bb[12], STAT(12), preact, nullptr,
                                       bfB, N3, zrow, stream);
    layer<64, 64, 3, true, false, 64>(bfB, rbc4, WT[13], G[13], Bb[13], STAT(13), preact, f4,
                                      nullptr, N4, zrow, stream);
#undef STAT
}

// Round 7
// 721.012 us; speedup vs baseline: 2.3632x; 2.3632x over previous
//
#include <hip/hip_runtime.h>

#define BN_EPS 1e-3f
#define NREP 16  // BN stat replicas

typedef __attribute__((ext_vector_type(8))) short short8;
typedef __attribute__((ext_vector_type(4))) float float4v;

__device__ __forceinline__ short f2bf(float f) {
    unsigned u = __float_as_uint(f);
    unsigned r = (u + 0x7FFFu + ((u >> 16) & 1u)) >> 16;
    return (short)r;
}

// s_waitcnt vmcnt(N) only
template <int N>
__device__ __forceinline__ void waitcnt_vm() {
    __builtin_amdgcn_s_waitcnt(0xF70 | (N & 15) | ((N >> 4) << 14));
}

// raw s_barrier (no compiler vmcnt(0) drain; we wait explicitly)
__device__ __forceinline__ void wave_barrier() { asm volatile("s_barrier" ::: "memory"); }

// async global -> LDS, 16B/lane; lds dst wave-uniform base + lane*16
__device__ __forceinline__ void dma16(const short* g, short* l) {
    __builtin_amdgcn_global_load_lds((const __attribute__((address_space(1))) void*)g,
                                     (__attribute__((address_space(3))) void*)l, 16, 0, 0);
}

// ---------------- small utility kernels ----------------

__global__ __launch_bounds__(256) void zero_kernel(float* p, int n) {
    int i = blockIdx.x * 256 + threadIdx.x;
    if (i < n) p[i] = 0.f;
}

__global__ __launch_bounds__(256) void copy_kernel(const float* __restrict__ in,
                                                   float* __restrict__ out, int n) {
    int i = blockIdx.x * 256 + threadIdx.x;
    if (i < n) out[i] = in[i];
}

__global__ __launch_bounds__(256) void zero_rows_kernel(short* a, short* b, long maxN) {
    int t = threadIdx.x;
    if (t < 32) a[maxN * 32 + t] = 0;
    else if (t < 96) a[maxN * 64 + (t - 32)] = 0;
    else if (t < 128) b[maxN * 32 + (t - 96)] = 0;
    else if (t < 192) b[maxN * 64 + (t - 128)] = 0;
}

__global__ __launch_bounds__(256) void xyz_kernel(const int* __restrict__ coords,
                                                  float* __restrict__ out, int N,
                                                  float sx, float sy, float sz) {
    int n = blockIdx.x * 256 + threadIdx.x;
    if (n >= N) return;
    int4 c = ((const int4*)coords)[n];
    out[n * 3 + 0] = c.w * sx;
    out[n * 3 + 1] = c.z * sy - 40.0f;
    out[n * 3 + 2] = c.y * sz - 3.0f;
}

__global__ __launch_bounds__(256) void convert_f0(const float* __restrict__ f,
                                                  short* __restrict__ dst, int N) {
    int i = blockIdx.x * 256 + threadIdx.x;
    if (i >= N * 32) return;
    int c = i & 31, n = i >> 5;
    dst[i] = (c < 4) ? f2bf(f[n * 4 + c]) : (short)0;
}

// ---- weight prep: W [K][CI][CO] fp32 -> Wt [K][c*CT+t][quad][l16][8] bf16 ----
struct PrepAll {
    const float* src[14];
    short* dst[14];
    int CI[14];
    int CO[14];
    int CHP[14];
    int cum[15];
};

__global__ __launch_bounds__(256) void prep_all_kernel(PrepAll d) {
    int i = blockIdx.x * 256 + threadIdx.x;
    if (i >= d.cum[14]) return;
    int l = 0;
    while (l < 13 && i >= d.cum[l + 1]) ++l;
    int f = i - d.cum[l];
    int CO = d.CO[l], CI = d.CI[l];
    int NCH = d.CHP[l] / 32, CT = CO / 16;
    int e = f & 7;
    int u = f >> 3;
    int l16 = u & 15;
    int q = (u >> 4) & 3;
    int u2 = u >> 6;
    int t = u2 % CT;
    int c = (u2 / CT) % NCH;
    int k = u2 / (CT * NCH);
    int ci = c * 32 + q * 8 + e;
    int co = t * 16 + l16;
    float v = (ci < CI) ? d.src[l][((size_t)k * CI + ci) * CO + co] : 0.f;
    d.dst[l][f] = f2bf(v);
}

// per-k A fragments for one wave (32 rows x CHP), held in VGPRs
struct ASet {
    short8 v0, v1, v2, v3;  // (mt0,c0) (mt0,c1) (mt1,c0) (mt1,c1)
};

// ---------------- hybrid MFMA sparse conv: 8 waves x 32 rows, B-only LDS ring ------
// 512-thread blocks (ROWS=256) double the resident waves/CU vs the 256-thread
// version (LDS 52.5KB -> 3 blocks/CU -> up to 24 waves/CU) to hide gather
// latency with TLP. A: direct global->VGPR gathers, depth-2 pipeline; B: 3-slot
// LDS ring via global_load_lds, split across 8 waves; per-block active-k
// compaction (effective only at low-density layers).
template <int CHP, int CO, int K>
__global__ __launch_bounds__(512, 4) void sconv_hyb(const short* __restrict__ feat,
                                                    const int* __restrict__ rb,
                                                    const short* __restrict__ Wt,
                                                    float* __restrict__ out,
                                                    float* __restrict__ stats, int N, int zrow) {
    constexpr int NCH = CHP / 32;
    constexpr int CT = CO / 16;
    constexpr int BTILE = CO * CHP;    // shorts
    constexpr int NB = BTILE / 512;    // B DMA insts per tile (1KB each)
    constexpr int A = 2 * NCH;         // A gather loads per wave per tile
    constexpr int ROWS = 256;
    constexpr int WAVES = 8;
    constexpr int B0 = NB / WAVES;     // per-wave B share (low)
    constexpr int BR = NB % WAVES;     // waves with one extra B DMA

    __shared__ __align__(16) short ldsB[3 * BTILE];
    __shared__ int sIdx[K * ROWS];
    __shared__ int sFlag[K];
    __shared__ int sKl[K];
    __shared__ int sKn;

    const int tid = threadIdx.x;
    const int w = tid >> 6;
    const int lane = tid & 63;
    const int quad = lane >> 4;
    const int l16 = lane & 15;
    const int m0 = blockIdx.x * ROWS;

    if (tid < K) sFlag[tid] = 0;
    __syncthreads();
    for (int e = tid; e < K * ROWS; e += 512) {
        int r = m0 + (e & (ROWS - 1));
        int v = (r < N) ? __builtin_nontemporal_load(&rb[(size_t)(e >> 8) * N + r]) : -1;
        sIdx[e] = v;
        if (v >= 0) sFlag[e >> 8] = 1;  // benign race: same value
    }
    __syncthreads();
    // wave 0: compact active k list via ballot + prefix popcount
    if (w == 0) {
        int f = (lane < K) ? sFlag[lane] : 0;
        unsigned long long m = __ballot(f != 0);
        if (f) sKl[__popcll(m & ((1ull << lane) - 1ull))] = lane;
        if (lane == 0) sKn = (int)__popcll(m);
    }
    __syncthreads();
    const int nk = sKn;

    const short* fquad = feat + quad * 8;

    auto issueB = [&](int kp, int slot) {
        const short* wk = Wt + (size_t)kp * BTILE + lane * 8;
        short* bb = ldsB + slot * BTILE;
#pragma unroll
        for (int jj = 0; jj < (NB + WAVES - 1) / WAVES; ++jj) {
            int j = jj * WAVES + w;
            if (j < NB) dma16(wk + j * 512, bb + j * 512);
        }
    };
    auto issueA = [&](int kp) {
        ASet s;
        int i0 = sIdx[kp * ROWS + w * 32 + l16];
        int i1 = sIdx[kp * ROWS + w * 32 + 16 + l16];
        const short* p0 = fquad + (size_t)(i0 < 0 ? zrow : i0) * CHP;
        const short* p1 = fquad + (size_t)(i1 < 0 ? zrow : i1) * CHP;
        s.v0 = *(const short8*)p0;
        s.v2 = *(const short8*)p1;
        if constexpr (NCH == 2) {
            s.v1 = *(const short8*)(p0 + 32);
            s.v3 = *(const short8*)(p1 + 32);
        } else {
            s.v1 = (short8)0;
            s.v3 = (short8)0;
        }
        return s;
    };

    float4v acc[2][CT];
#pragma unroll
    for (int mt = 0; mt < 2; ++mt)
#pragma unroll
        for (int t = 0; t < CT; ++t) acc[mt][t] = (float4v)0.f;

    // prologue: up to 2 active tiles in flight (order per tile: B then A)
    ASet sA{}, sB{}, sC{};
    if (nk > 0) {
        issueB(sKl[0], 0);
        sA = issueA(sKl[0]);
    }
    if (nk > 1) {
        issueB(sKl[1], 1);
        sB = issueA(sKl[1]);
    }

    int slotRd = 0, slotWr = 2;
    for (int i = 0; i < nk; ++i) {
        if (i < nk - 1) {
            // wait until only the NEWEST tile's ops (own B share + own A) remain
            if (BR > 0 && w < BR) waitcnt_vm<B0 + 1 + A>();
            else waitcnt_vm<B0 + A>();
        } else {
            waitcnt_vm<0>();
        }
        __builtin_amdgcn_sched_barrier(0);
        wave_barrier();  // all waves' B(i) shares landed; all done reading slot i-1
        if (i + 2 < nk) {
            issueB(sKl[i + 2], slotWr);
            sC = issueA(sKl[i + 2]);
        }
        // compute tile i: B from LDS slot, A from sA registers
        const short* bb = ldsB + slotRd * BTILE;
#pragma unroll
        for (int c = 0; c < NCH; ++c) {
#pragma unroll
            for (int t = 0; t < CT; ++t) {
                short8 bf = *(const short8*)(bb + ((c * CT + t) * 64 + quad * 16 + l16) * 8);
#pragma unroll
                for (int mt = 0; mt < 2; ++mt) {
                    short8 af = (mt == 0) ? ((c == 0) ? sA.v0 : sA.v1)
                                          : ((c == 0) ? sA.v2 : sA.v3);
                    acc[mt][t] = __builtin_amdgcn_mfma_f32_16x16x32_bf16(af, bf, acc[mt][t], 0,
                                                                         0, 0);
                }
            }
        }
        sA = sB;
        sB = sC;
        slotRd = (slotRd == 2) ? 0 : slotRd + 1;
        slotWr = (slotWr == 2) ? 0 : slotWr + 1;
    }

    // stores: D layout col = lane&15, row = quad*4 + reg. Plain (cached) stores:
    // L2 assembles full lines; bn_apply re-reads from L2.
#pragma unroll
    for (int mt = 0; mt < 2; ++mt)
#pragma unroll
        for (int t = 0; t < CT; ++t) {
            int col = t * 16 + l16;
#pragma unroll
            for (int r = 0; r < 4; ++r) {
                int orow = m0 + w * 32 + mt * 16 + quad * 4 + r;
                if (orow < N) out[(size_t)orow * CO + col] = acc[mt][t][r];
            }
        }

    // block-level BN stats -> one atomic per channel per block.
    // (rows >= N and idx<0 gathers hit the zero row, so their acc entries are 0)
    __syncthreads();
    float* red = (float*)ldsB;  // [WAVES][2*CO]
#pragma unroll
    for (int t = 0; t < CT; ++t) {
        float s = 0.f, ss = 0.f;
#pragma unroll
        for (int mt = 0; mt < 2; ++mt)
#pragma unroll
            for (int r = 0; r < 4; ++r) {
                float v = acc[mt][t][r];
                s += v;
                ss += v * v;
            }
        s += __shfl_xor(s, 16);
        s += __shfl_xor(s, 32);
        ss += __shfl_xor(ss, 16);
        ss += __shfl_xor(ss, 32);
        if (lane < 16) {
            red[w * 2 * CO + t * 16 + lane] = s;
            red[w * 2 * CO + CO + t * 16 + lane] = ss;
        }
    }
    __syncthreads();
    if (tid < 2 * CO) {
        float v = 0.f;
#pragma unroll
        for (int r = 0; r < WAVES; ++r) v += red[r * 2 * CO + tid];
        float* st = stats + (size_t)(blockIdx.x & (NREP - 1)) * 128;
        atomicAdd(&st[(tid < CO) ? tid : (64 + tid - CO)], v);
    }
}

// ---------------- BN apply + ReLU, 8-wide vectorized ----------------
template <int COUT, int CHPN, bool F32OUT, bool BFOUT>
__global__ __launch_bounds__(256) void bn_apply(const float* __restrict__ x,
                                                const float* __restrict__ stats,
                                                const float* __restrict__ g,
                                                const float* __restrict__ b,
                                                float* __restrict__ fout,
                                                short* __restrict__ bfout, int N) {
    constexpr int CW = BFOUT ? CHPN : COUT;
    constexpr int CV = CW / 8;  // short8/float8 groups per row
    __shared__ float ssc[COUT];
    __shared__ float ssh[COUT];
    int tid = threadIdx.x;
    if (tid < COUT) {
        float s = 0.f, q = 0.f;
#pragma unroll
        for (int r = 0; r < NREP; ++r) {
            s += stats[r * 128 + tid];
            q += stats[r * 128 + 64 + tid];
        }
        float inv = 1.0f / (float)N;
        float m = s * inv;
        float v = q * inv - m * m;
        float sc = g[tid] / sqrtf(v + BN_EPS);
        ssc[tid] = sc;
        ssh[tid] = b[tid] - m * sc;
    }
    __syncthreads();
    long i = (long)blockIdx.x * 256 + tid;
    if (i >= (long)N * CV) return;
    int c8 = (int)(i % CV);
    long n = i / CV;
    int cb = c8 * 8;
    float y[8];
#pragma unroll
    for (int j = 0; j < 8; ++j) y[j] = 0.f;
    if (cb < COUT) {
        const float4v* xr = (const float4v*)(x + n * COUT + cb);
        float4v a0 = xr[0];
        float4v a1 = xr[1];
#pragma unroll
        for (int j = 0; j < 4; ++j) {
            y[j] = fmaxf(a0[j] * ssc[cb + j] + ssh[cb + j], 0.f);
            y[4 + j] = fmaxf(a1[j] * ssc[cb + 4 + j] + ssh[cb + 4 + j], 0.f);
        }
        if constexpr (F32OUT) {
            float* fo = fout + n * COUT + cb;
            if ((((unsigned long long)fout) & 15ull) == 0) {  // uniform branch
                float4v o0, o1;
#pragma unroll
                for (int j = 0; j < 4; ++j) {
                    o0[j] = y[j];
                    o1[j] = y[4 + j];
                }
                ((float4v*)fo)[0] = o0;
                ((float4v*)fo)[1] = o1;
            } else {
#pragma unroll
                for (int j = 0; j < 8; ++j) fo[j] = y[j];
            }
        }
    }
    if constexpr (BFOUT) {
        short8 p;
#pragma unroll
        for (int j = 0; j < 8; ++j) p[j] = f2bf(y[j]);
        *(short8*)(bfout + n * CHPN + cb) = p;
    }
}

// ---------------- host helpers ----------------

template <int CHP, int CO, int K>
static void conv(const short* fin, const int* rb, const short* wt, float* preact, float* stats,
                 int N, int zrow, hipStream_t stream) {
    dim3 grid((N + 255) / 256);
    hipLaunchKernelGGL((sconv_hyb<CHP, CO, K>), grid, dim3(512), 0, stream, fin, rb, wt, preact,
                       stats, N, zrow);
}

template <int COUT, int CHPN, bool F32OUT, bool BFOUT>
static void apply(const float* preact, const float* stats, const float* g, const float* b,
                  float* fout, short* bfout, int N, hipStream_t stream) {
    constexpr int CW = BFOUT ? CHPN : COUT;
    constexpr int CV = CW / 8;
    int blocks = (int)(((long)N * CV + 255) / 256);
    hipLaunchKernelGGL((bn_apply<COUT, CHPN, F32OUT, BFOUT>), dim3(blocks), dim3(256), 0, stream,
                       preact, stats, g, b, fout, bfout, N);
}

extern "C" void kernel_launch(void* const* d_in, const int* in_sizes, int n_in, void* d_out,
                              int out_size, void* d_ws, size_t ws_size, hipStream_t stream) {
    const float* features = (const float*)d_in[0];
    const float* W[14];
    const float* G[14];
    const float* Bb[14];
    for (int i = 0; i < 14; ++i) {
        W[i] = (const float*)d_in[1 + 3 * i];
        G[i] = (const float*)d_in[2 + 3 * i];
        Bb[i] = (const float*)d_in[3 + 3 * i];
    }
    const int* coords0 = (const int*)d_in[43];
    const int* coords1 = (const int*)d_in[44];
    const int* coords2 = (const int*)d_in[45];
    const int* coords3 = (const int*)d_in[46];
    const int* rb0 = (const int*)d_in[47];
    const int* rbc1 = (const int*)d_in[48];
    const int* rb1 = (const int*)d_in[49];
    const int* rbc2 = (const int*)d_in[50];
    const int* rb2 = (const int*)d_in[51];
    const int* rbc3 = (const int*)d_in[52];
    const int* rb3 = (const int*)d_in[53];
    const int* rbc4 = (const int*)d_in[54];

    const int N0 = in_sizes[0] / 4;
    const int N1 = in_sizes[44] / 4;
    const int N2 = in_sizes[45] / 4;
    const int N3 = in_sizes[46] / 4;
    const int N4 = in_sizes[54] / 3;

    float* out = (float*)d_out;
    long off = 0;
    float* xyz0 = out + off; off += (long)N0 * 3;
    float* f0   = out + off; off += (long)N0 * 4;
    float* xyz1 = out + off; off += (long)N1 * 3;
    float* f1   = out + off; off += (long)N1 * 32;
    float* xyz2 = out + off; off += (long)N2 * 3;
    float* f2   = out + off; off += (long)N2 * 64;
    float* xyz3 = out + off; off += (long)N3 * 3;
    float* f3   = out + off; off += (long)N3 * 64;
    float* f4   = out + off;

    long maxN = N0;
    if (N1 > maxN) maxN = N1;
    if (N2 > maxN) maxN = N2;
    if (N3 > maxN) maxN = N3;
    if (N4 > maxN) maxN = N4;
    const int zrow = (int)maxN;

    float* preact = (float*)d_ws;                         // maxN*64 fp32
    float* statsBase = preact + (size_t)maxN * 64;        // 14 * NREP * 128 fp32
    short* bfA = (short*)(statsBase + 14 * NREP * 128);   // (maxN+1)*64 bf16
    short* bfB = bfA + (size_t)(maxN + 1) * 64;           // (maxN+1)*64 bf16
    short* wtBase = bfB + (size_t)(maxN + 1) * 64;        // swizzled bf16 weights

    static const int KK[14] = {27, 27, 27, 27, 27, 27, 27, 27, 27, 27, 27, 27, 27, 3};
    static const int CI[14] = {4, 16, 16, 32, 32, 32, 64, 64, 64, 64, 64, 64, 64, 64};
    static const int CO[14] = {16, 16, 32, 32, 32, 64, 64, 64, 64, 64, 64, 64, 64, 64};
    short* WT[14];
    PrepAll pd;
    {
        size_t o = 0;
        int cum = 0;
        for (int l = 0; l < 14; ++l) {
            WT[l] = wtBase + o;
            int chp = CI[l] <= 32 ? 32 : 64;
            pd.src[l] = W[l];
            pd.dst[l] = WT[l];
            pd.CI[l] = CI[l];
            pd.CO[l] = CO[l];
            pd.CHP[l] = chp;
            pd.cum[l] = cum;
            cum += KK[l] * CO[l] * chp;
            o += (size_t)KK[l] * CO[l] * chp;
        }
        pd.cum[14] = cum;
    }

    int nstats = 14 * NREP * 128;
    hipLaunchKernelGGL(zero_kernel, dim3((nstats + 255) / 256), dim3(256), 0, stream, statsBase,
                       nstats);
    hipLaunchKernelGGL(zero_rows_kernel, dim3(1), dim3(256), 0, stream, bfA, bfB, maxN);
    hipLaunchKernelGGL(prep_all_kernel, dim3((pd.cum[14] + 255) / 256), dim3(256), 0, stream, pd);

    hipLaunchKernelGGL(copy_kernel, dim3((N0 * 4 + 255) / 256), dim3(256), 0, stream, features, f0,
                       N0 * 4);
    hipLaunchKernelGGL(xyz_kernel, dim3((N0 + 255) / 256), dim3(256), 0, stream, coords0, xyz0, N0,
                       0.05f, 0.05f, 0.1f);
    hipLaunchKernelGGL(xyz_kernel, dim3((N1 + 255) / 256), dim3(256), 0, stream, coords1, xyz1, N1,
                       0.1f, 0.1f, 0.2f);
    hipLaunchKernelGGL(xyz_kernel, dim3((N2 + 255) / 256), dim3(256), 0, stream, coords2, xyz2, N2,
                       0.2f, 0.2f, 0.4f);
    hipLaunchKernelGGL(xyz_kernel, dim3((N3 + 255) / 256), dim3(256), 0, stream, coords3, xyz3, N3,
                       0.4f, 0.4f, 0.8f);
    hipLaunchKernelGGL(convert_f0, dim3((N0 * 32 + 255) / 256), dim3(256), 0, stream, features,
                       bfA, N0);

    float* st = statsBase;
#define STAT(l) (st + (size_t)(l)*NREP * 128)

    conv<32, 16, 27>(bfA, rb0, WT[0], preact, STAT(0), N0, zrow, stream);
    apply<16, 32, false, true>(preact, STAT(0), G[0], Bb[0], nullptr, bfB, N0, stream);
    conv<32, 16, 27>(bfB, rb0, WT[1], preact, STAT(1), N0, zrow, stream);
    apply<16, 32, false, true>(preact, STAT(1), G[1], Bb[1], nullptr, bfA, N0, stream);
    conv<32, 32, 27>(bfA, rbc1, WT[2], preact, STAT(2), N1, zrow, stream);
    apply<32, 32, true, true>(preact, STAT(2), G[2], Bb[2], f1, bfB, N1, stream);

    conv<32, 32, 27>(bfB, rb1, WT[3], preact, STAT(3), N1, zrow, stream);
    apply<32, 32, false, true>(preact, STAT(3), G[3], Bb[3], nullptr, bfA, N1, stream);
    conv<32, 32, 27>(bfA, rb1, WT[4], preact, STAT(4), N1, zrow, stream);
    apply<32, 32, false, true>(preact, STAT(4), G[4], Bb[4], nullptr, bfB, N1, stream);
    conv<32, 64, 27>(bfB, rbc2, WT[5], preact, STAT(5), N2, zrow, stream);
    apply<64, 64, true, true>(preact, STAT(5), G[5], Bb[5], f2, bfA, N2, stream);

    conv<64, 64, 27>(bfA, rb2, WT[6], preact, STAT(6), N2, zrow, stream);
    apply<64, 64, false, true>(preact, STAT(6), G[6], Bb[6], nullptr, bfB, N2, stream);
    conv<64, 64, 27>(bfB, rb2, WT[7], preact, STAT(7), N2, zrow, stream);
    apply<64, 64, false, true>(preact, STAT(7), G[7], Bb[7], nullptr, bfA, N2, stream);
    conv<64, 64, 27>(bfA, rb2, WT[8], preact, STAT(8), N2, zrow, stream);
    apply<64, 64, false, true>(preact, STAT(8), G[8], Bb[8], nullptr, bfB, N2, stream);
    conv<64, 64, 27>(bfB, rbc3, WT[9], preact, STAT(9), N3, zrow, stream);
    apply<64, 64, true, true>(preact, STAT(9), G[9], Bb[9], f3, bfA, N3, stream);

    conv<64, 64, 27>(bfA, rb3, WT[10], preact, STAT(10), N3, zrow, stream);
    apply<64, 64, false, true>(preact, STAT(10), G[10], Bb[10], nullptr, bfB, N3, stream);
    conv<64, 64, 27>(bfB, rb3, WT[11], preact, STAT(11), N3, zrow, stream);
    apply<64, 64, false, true>(preact, STAT(11), G[11], Bb[11], nullptr, bfA, N3, stream);
    conv<64, 64, 27>(bfA, rb3, WT[12], preact, STAT(12), N3, zrow, stream);
    apply<64, 64, false, true>(preact, STAT(12), G[12], Bb[12], nullptr, bfB, N3, stream);
    conv<64, 64, 3>(bfB, rbc4, WT[13], preact, STAT(13), N4, zrow, stream);
    apply<64, 64, true, false>(preact, STAT(13), G[13], Bb[13], f4, nullptr, N4, stream);
#undef STAT
}